// Round 1
// baseline (849.170 us; speedup 1.0000x reference)
//
#include <hip/hip_runtime.h>
#include <math.h>

#define N_NODES 100000
#define N_EDGES 1600000
#define D_IN 256
#define N_HEADS 4
#define D_OUT 32
#define D_HID 128   // N_HEADS*D_OUT
#define NEG_SLOPE 0.2f

// ---------------- GEMM: ft[N,128] = x[N,256] @ w[128,256]^T ----------------
// BM=64 rows, BN=128 (all cols), BK=32, 256 threads
__global__ __launch_bounds__(256) void k_gemm(const float* __restrict__ x,
                                              const float* __restrict__ w,
                                              float* __restrict__ ft) {
  __shared__ float xs[32][68];   // [k][r], padded row stride 68 (16B-aligned)
  __shared__ float ws[32][132];  // [k][j], padded row stride 132 (16B-aligned)
  int t = threadIdx.x;
  int rowBase = blockIdx.x * 64;
  int r0 = (t >> 5) * 8;
  int c0 = (t & 31) * 4;
  float acc[8][4];
  #pragma unroll
  for (int i = 0; i < 8; ++i)
    #pragma unroll
    for (int j = 0; j < 4; ++j) acc[i][j] = 0.f;

  for (int kb = 0; kb < D_IN; kb += 32) {
    // load x tile: 64 rows x 32 k (2048 floats, 2 float4 per thread)
    #pragma unroll
    for (int p = 0; p < 2; ++p) {
      int li = p * 1024 + t * 4;
      int r = li >> 5;
      int kk = li & 31;
      int row = rowBase + r;
      float4 v = make_float4(0.f, 0.f, 0.f, 0.f);
      if (row < N_NODES) v = *(const float4*)&x[(size_t)row * D_IN + kb + kk];
      xs[kk + 0][r] = v.x; xs[kk + 1][r] = v.y; xs[kk + 2][r] = v.z; xs[kk + 3][r] = v.w;
    }
    // load w tile: 128 cols x 32 k (4096 floats, 4 float4 per thread)
    #pragma unroll
    for (int p = 0; p < 4; ++p) {
      int li = p * 1024 + t * 4;
      int j = li >> 5;
      int kk = li & 31;
      float4 v = *(const float4*)&w[(size_t)j * D_IN + kb + kk];
      ws[kk + 0][j] = v.x; ws[kk + 1][j] = v.y; ws[kk + 2][j] = v.z; ws[kk + 3][j] = v.w;
    }
    __syncthreads();
    #pragma unroll
    for (int k = 0; k < 32; ++k) {
      float4 wv = *(const float4*)&ws[k][c0];
      float4 xa = *(const float4*)&xs[k][r0];
      float4 xb = *(const float4*)&xs[k][r0 + 4];
      float xr[8] = {xa.x, xa.y, xa.z, xa.w, xb.x, xb.y, xb.z, xb.w};
      #pragma unroll
      for (int i = 0; i < 8; ++i) {
        acc[i][0] += xr[i] * wv.x;
        acc[i][1] += xr[i] * wv.y;
        acc[i][2] += xr[i] * wv.z;
        acc[i][3] += xr[i] * wv.w;
      }
    }
    __syncthreads();
  }
  #pragma unroll
  for (int i = 0; i < 8; ++i) {
    int row = rowBase + r0 + i;
    if (row < N_NODES) {
      float4 v = make_float4(acc[i][0], acc[i][1], acc[i][2], acc[i][3]);
      *(float4*)&ft[(size_t)row * D_HID + c0] = v;
    }
  }
}

// ---------------- per-node attention logits el,er [N,4] ----------------
__global__ void k_eler(const float* __restrict__ ft,
                       const float* __restrict__ al,
                       const float* __restrict__ ar,
                       float* __restrict__ el, float* __restrict__ er) {
  int gid = blockIdx.x * blockDim.x + threadIdx.x;
  if (gid >= N_NODES * N_HEADS) return;
  int n = gid >> 2, h = gid & 3;
  const float* f = &ft[(size_t)n * D_HID + h * D_OUT];
  const float* alh = &al[h * D_OUT];
  const float* arh = &ar[h * D_OUT];
  float sl = 0.f, sr = 0.f;
  #pragma unroll
  for (int i = 0; i < D_OUT; i += 4) {
    float4 fv = *(const float4*)&f[i];
    float4 av = *(const float4*)&alh[i];
    float4 bv = *(const float4*)&arh[i];
    sl += fv.x * av.x + fv.y * av.y + fv.z * av.z + fv.w * av.w;
    sr += fv.x * bv.x + fv.y * bv.y + fv.z * bv.z + fv.w * bv.w;
  }
  el[gid] = sl;
  er[gid] = sr;
}

// ---------------- counting sort by dst ----------------
__global__ void k_hist(const int* __restrict__ dst, int* __restrict__ cnt) {
  int gid = blockIdx.x * blockDim.x + threadIdx.x;
  if (gid < N_EDGES) atomicAdd(&cnt[dst[gid]], 1);
}

__global__ __launch_bounds__(1024) void k_scan(const int* __restrict__ cnt,
                                               int* __restrict__ offs,
                                               int* __restrict__ cursor) {
  __shared__ int ss[1024];
  int t = threadIdx.x;
  const int STRIP = (N_NODES + 1023) / 1024; // 98
  int s0 = t * STRIP;
  int sum = 0;
  for (int i = 0; i < STRIP; ++i) {
    int idx = s0 + i;
    if (idx < N_NODES) sum += cnt[idx];
  }
  ss[t] = sum;
  __syncthreads();
  for (int d = 1; d < 1024; d <<= 1) {
    int v = (t >= d) ? ss[t - d] : 0;
    __syncthreads();
    ss[t] += v;
    __syncthreads();
  }
  int run = (t == 0) ? 0 : ss[t - 1];
  for (int i = 0; i < STRIP; ++i) {
    int idx = s0 + i;
    if (idx < N_NODES) {
      offs[idx] = run;
      cursor[idx] = run;
      run += cnt[idx];
    }
  }
  if (t == 0) offs[N_NODES] = N_EDGES;
}

__global__ void k_scatter(const int* __restrict__ src, const int* __restrict__ dst,
                          int* __restrict__ cursor, int* __restrict__ ssrc) {
  int gid = blockIdx.x * blockDim.x + threadIdx.x;
  if (gid < N_EDGES) {
    int d = dst[gid];
    int pos = atomicAdd(&cursor[d], 1);
    ssrc[pos] = src[gid];
  }
}

// ---------------- per-node softmax + weighted aggregation ----------------
// one 64-lane wave per node; lane handles features 2*lane, 2*lane+1
__global__ __launch_bounds__(256) void k_agg(const int* __restrict__ offs,
                                             const int* __restrict__ ssrc,
                                             const float* __restrict__ ft,
                                             const float* __restrict__ el,
                                             const float* __restrict__ er,
                                             float* __restrict__ out) {
  int wave = threadIdx.x >> 6;
  int lane = threadIdx.x & 63;
  int n = blockIdx.x * 4 + wave;
  if (n >= N_NODES) return;
  int start = offs[n], end = offs[n + 1];
  int f0 = lane * 2;
  int hh = lane >> 4;  // head owning features f0,f0+1
  float2 acc = {0.f, 0.f};
  if (start < end) {
    float4 er4 = *(const float4*)&er[n * 4];
    float erh[4] = {er4.x, er4.y, er4.z, er4.w};
    // pass 1: per-head max over incoming edges
    float m[4] = {-INFINITY, -INFINITY, -INFINITY, -INFINITY};
    for (int c = start; c < end; c += 64) {
      int i = c + lane;
      bool valid = i < end;
      int s = valid ? ssrc[i] : 0;
      float4 e4 = *(const float4*)&el[s * 4];
      float ee[4] = {e4.x, e4.y, e4.z, e4.w};
      #pragma unroll
      for (int h = 0; h < 4; ++h) {
        float v = ee[h] + erh[h];
        v = v > 0.f ? v : NEG_SLOPE * v;
        if (!valid) v = -INFINITY;
        m[h] = fmaxf(m[h], v);
      }
    }
    #pragma unroll
    for (int h = 0; h < 4; ++h)
      #pragma unroll
      for (int o = 32; o > 0; o >>= 1) m[h] = fmaxf(m[h], __shfl_xor(m[h], o));
    // pass 2: denominator
    float den[4] = {0.f, 0.f, 0.f, 0.f};
    for (int c = start; c < end; c += 64) {
      int i = c + lane;
      bool valid = i < end;
      int s = valid ? ssrc[i] : 0;
      float4 e4 = *(const float4*)&el[s * 4];
      float ee[4] = {e4.x, e4.y, e4.z, e4.w};
      #pragma unroll
      for (int h = 0; h < 4; ++h) {
        float v = ee[h] + erh[h];
        v = v > 0.f ? v : NEG_SLOPE * v;
        den[h] += valid ? __expf(v - m[h]) : 0.f;
      }
    }
    #pragma unroll
    for (int h = 0; h < 4; ++h)
      #pragma unroll
      for (int o = 32; o > 0; o >>= 1) den[h] += __shfl_xor(den[h], o);
    float invd = 1.f / den[hh];
    // pass 3: weighted gather-accumulate
    for (int c = start; c < end; c += 64) {
      int i = c + lane;
      bool valid = i < end;
      int s = valid ? ssrc[i] : 0;
      float4 e4 = *(const float4*)&el[s * 4];
      float ee[4] = {e4.x, e4.y, e4.z, e4.w};
      float ex[4];
      #pragma unroll
      for (int h = 0; h < 4; ++h) {
        float v = ee[h] + erh[h];
        v = v > 0.f ? v : NEG_SLOPE * v;
        ex[h] = __expf(v - m[h]);
      }
      int cnt2 = min(64, end - c);
      for (int j = 0; j < cnt2; ++j) {
        int sj = __shfl(s, j);
        float a0 = __shfl(ex[0], j);
        float a1 = __shfl(ex[1], j);
        float a2 = __shfl(ex[2], j);
        float a3 = __shfl(ex[3], j);
        float ah = hh == 0 ? a0 : (hh == 1 ? a1 : (hh == 2 ? a2 : a3));
        ah *= invd;
        float2 v = *(const float2*)&ft[(size_t)sj * D_HID + f0];
        acc.x += ah * v.x;
        acc.y += ah * v.y;
      }
    }
  }
  *(float2*)&out[(size_t)n * D_HID + f0] = acc;
}

extern "C" void kernel_launch(void* const* d_in, const int* in_sizes, int n_in,
                              void* d_out, int out_size, void* d_ws, size_t ws_size,
                              hipStream_t stream) {
  const float* x      = (const float*)d_in[0];
  const float* fc_w   = (const float*)d_in[1];
  const float* attn_l = (const float*)d_in[2];
  const float* attn_r = (const float*)d_in[3];
  const int*   src    = (const int*)d_in[4];
  const int*   dst    = (const int*)d_in[5];
  float* out = (float*)d_out;

  char* wsp = (char*)d_ws;
  size_t off = 0;
  auto alloc = [&](size_t bytes) {
    void* p = wsp + off;
    off = (off + bytes + 255) & ~(size_t)255;
    return p;
  };
  float* ft     = (float*)alloc((size_t)N_NODES * D_HID * 4);
  float* el     = (float*)alloc((size_t)N_NODES * 4 * 4);
  float* er     = (float*)alloc((size_t)N_NODES * 4 * 4);
  int*   cnt    = (int*)alloc((size_t)N_NODES * 4);
  int*   offs   = (int*)alloc((size_t)(N_NODES + 1) * 4);
  int*   cursor = (int*)alloc((size_t)N_NODES * 4);
  int*   ssrc   = (int*)alloc((size_t)N_EDGES * 4);

  hipMemsetAsync(cnt, 0, (size_t)N_NODES * 4, stream);
  k_gemm<<<(N_NODES + 63) / 64, 256, 0, stream>>>(x, fc_w, ft);
  k_eler<<<(N_NODES * N_HEADS + 255) / 256, 256, 0, stream>>>(ft, attn_l, attn_r, el, er);
  k_hist<<<(N_EDGES + 255) / 256, 256, 0, stream>>>(dst, cnt);
  k_scan<<<1, 1024, 0, stream>>>(cnt, offs, cursor);
  k_scatter<<<(N_EDGES + 255) / 256, 256, 0, stream>>>(src, dst, cursor, ssrc);
  k_agg<<<(N_NODES + 3) / 4, 256, 0, stream>>>(offs, ssrc, ft, el, er, out);
}

// Round 2
// 602.757 us; speedup vs baseline: 1.4088x; 1.4088x over previous
//
#include <hip/hip_runtime.h>
#include <math.h>

#define N_NODES 100000
#define N_EDGES 1600000
#define D_IN 256
#define N_HEADS 4
#define D_OUT 32
#define D_HID 128   // N_HEADS*D_OUT
#define NEG_SLOPE 0.2f

#define SCAN_CHUNK 1024
#define N_SCAN_BLOCKS ((N_NODES + SCAN_CHUNK - 1) / SCAN_CHUNK)  // 98

// ---------------- GEMM: ft[N,128] = x[N,256] @ w[128,256]^T ----------------
// BM=64 rows, BN=128 (all cols), BK=32, 256 threads
__global__ __launch_bounds__(256) void k_gemm(const float* __restrict__ x,
                                              const float* __restrict__ w,
                                              float* __restrict__ ft) {
  __shared__ float xs[32][68];   // [k][r], padded
  __shared__ float ws[32][132];  // [k][j], padded
  int t = threadIdx.x;
  int rowBase = blockIdx.x * 64;
  int r0 = (t >> 5) * 8;
  int c0 = (t & 31) * 4;
  float acc[8][4];
  #pragma unroll
  for (int i = 0; i < 8; ++i)
    #pragma unroll
    for (int j = 0; j < 4; ++j) acc[i][j] = 0.f;

  for (int kb = 0; kb < D_IN; kb += 32) {
    #pragma unroll
    for (int p = 0; p < 2; ++p) {
      int li = p * 1024 + t * 4;
      int r = li >> 5;
      int kk = li & 31;
      int row = rowBase + r;
      float4 v = make_float4(0.f, 0.f, 0.f, 0.f);
      if (row < N_NODES) v = *(const float4*)&x[(size_t)row * D_IN + kb + kk];
      xs[kk + 0][r] = v.x; xs[kk + 1][r] = v.y; xs[kk + 2][r] = v.z; xs[kk + 3][r] = v.w;
    }
    #pragma unroll
    for (int p = 0; p < 4; ++p) {
      int li = p * 1024 + t * 4;
      int j = li >> 5;
      int kk = li & 31;
      float4 v = *(const float4*)&w[(size_t)j * D_IN + kb + kk];
      ws[kk + 0][j] = v.x; ws[kk + 1][j] = v.y; ws[kk + 2][j] = v.z; ws[kk + 3][j] = v.w;
    }
    __syncthreads();
    #pragma unroll
    for (int k = 0; k < 32; ++k) {
      float4 wv = *(const float4*)&ws[k][c0];
      float4 xa = *(const float4*)&xs[k][r0];
      float4 xb = *(const float4*)&xs[k][r0 + 4];
      float xr[8] = {xa.x, xa.y, xa.z, xa.w, xb.x, xb.y, xb.z, xb.w};
      #pragma unroll
      for (int i = 0; i < 8; ++i) {
        acc[i][0] += xr[i] * wv.x;
        acc[i][1] += xr[i] * wv.y;
        acc[i][2] += xr[i] * wv.z;
        acc[i][3] += xr[i] * wv.w;
      }
    }
    __syncthreads();
  }
  #pragma unroll
  for (int i = 0; i < 8; ++i) {
    int row = rowBase + r0 + i;
    if (row < N_NODES) {
      float4 v = make_float4(acc[i][0], acc[i][1], acc[i][2], acc[i][3]);
      *(float4*)&ft[(size_t)row * D_HID + c0] = v;
    }
  }
}

// ---------------- per-node attention logits el,er [N,4] ----------------
__global__ void k_eler(const float* __restrict__ ft,
                       const float* __restrict__ al,
                       const float* __restrict__ ar,
                       float* __restrict__ el, float* __restrict__ er) {
  int gid = blockIdx.x * blockDim.x + threadIdx.x;
  if (gid >= N_NODES * N_HEADS) return;
  int n = gid >> 2, h = gid & 3;
  const float* f = &ft[(size_t)n * D_HID + h * D_OUT];
  const float* alh = &al[h * D_OUT];
  const float* arh = &ar[h * D_OUT];
  float sl = 0.f, sr = 0.f;
  #pragma unroll
  for (int i = 0; i < D_OUT; i += 4) {
    float4 fv = *(const float4*)&f[i];
    float4 av = *(const float4*)&alh[i];
    float4 bv = *(const float4*)&arh[i];
    sl += fv.x * av.x + fv.y * av.y + fv.z * av.z + fv.w * av.w;
    sr += fv.x * bv.x + fv.y * bv.y + fv.z * bv.z + fv.w * bv.w;
  }
  el[gid] = sl;
  er[gid] = sr;
}

// ---------------- counting sort by dst ----------------
__global__ void k_hist(const int* __restrict__ dst, int* __restrict__ cnt) {
  int gid = blockIdx.x * blockDim.x + threadIdx.x;
  if (gid < N_EDGES) atomicAdd(&cnt[dst[gid]], 1);
}

// phase 1: per-block partial sums over 1024-node chunks
__global__ __launch_bounds__(256) void k_partial(const int* __restrict__ cnt,
                                                 int* __restrict__ part) {
  __shared__ int red[4];
  int b = blockIdx.x, t = threadIdx.x;
  int idx = b * SCAN_CHUNK + t * 4;
  int a0 = 0, a1 = 0, a2 = 0, a3 = 0;
  if (idx + 3 < N_NODES) {
    int4 v = *(const int4*)&cnt[idx];
    a0 = v.x; a1 = v.y; a2 = v.z; a3 = v.w;
  } else {
    if (idx + 0 < N_NODES) a0 = cnt[idx + 0];
    if (idx + 1 < N_NODES) a1 = cnt[idx + 1];
    if (idx + 2 < N_NODES) a2 = cnt[idx + 2];
    if (idx + 3 < N_NODES) a3 = cnt[idx + 3];
  }
  int s = a0 + a1 + a2 + a3;
  #pragma unroll
  for (int o = 32; o > 0; o >>= 1) s += __shfl_xor(s, o);
  if ((t & 63) == 0) red[t >> 6] = s;
  __syncthreads();
  if (t == 0) part[b] = red[0] + red[1] + red[2] + red[3];
}

// phase 2: exclusive scan of the 98 partials (one tiny block)
__global__ __launch_bounds__(128) void k_scanpart(const int* __restrict__ part,
                                                  int* __restrict__ epart) {
  __shared__ int ss[128];
  int t = threadIdx.x;
  int v = (t < N_SCAN_BLOCKS) ? part[t] : 0;
  ss[t] = v;
  __syncthreads();
  #pragma unroll
  for (int d = 1; d < 128; d <<= 1) {
    int u = (t >= d) ? ss[t - d] : 0;
    __syncthreads();
    ss[t] += u;
    __syncthreads();
  }
  epart[t] = (t == 0) ? 0 : ss[t - 1];
}

// phase 3: local exclusive scan + block offset -> offs, cursor
__global__ __launch_bounds__(256) void k_offsets(const int* __restrict__ cnt,
                                                 const int* __restrict__ epart,
                                                 int* __restrict__ offs,
                                                 int* __restrict__ cursor) {
  __shared__ int ss[256];
  int b = blockIdx.x, t = threadIdx.x;
  int idx = b * SCAN_CHUNK + t * 4;
  int a0 = 0, a1 = 0, a2 = 0, a3 = 0;
  if (idx + 3 < N_NODES) {
    int4 v = *(const int4*)&cnt[idx];
    a0 = v.x; a1 = v.y; a2 = v.z; a3 = v.w;
  } else {
    if (idx + 0 < N_NODES) a0 = cnt[idx + 0];
    if (idx + 1 < N_NODES) a1 = cnt[idx + 1];
    if (idx + 2 < N_NODES) a2 = cnt[idx + 2];
    if (idx + 3 < N_NODES) a3 = cnt[idx + 3];
  }
  int tsum = a0 + a1 + a2 + a3;
  ss[t] = tsum;
  __syncthreads();
  #pragma unroll
  for (int d = 1; d < 256; d <<= 1) {
    int u = (t >= d) ? ss[t - d] : 0;
    __syncthreads();
    ss[t] += u;
    __syncthreads();
  }
  int run = epart[b] + ((t == 0) ? 0 : ss[t - 1]);
  int o0 = run; run += a0;
  int o1 = run; run += a1;
  int o2 = run; run += a2;
  int o3 = run;
  if (idx + 3 < N_NODES) {
    int4 ov = make_int4(o0, o1, o2, o3);
    *(int4*)&offs[idx] = ov;
    *(int4*)&cursor[idx] = ov;
  } else {
    if (idx + 0 < N_NODES) { offs[idx + 0] = o0; cursor[idx + 0] = o0; }
    if (idx + 1 < N_NODES) { offs[idx + 1] = o1; cursor[idx + 1] = o1; }
    if (idx + 2 < N_NODES) { offs[idx + 2] = o2; cursor[idx + 2] = o2; }
  }
  if (b == 0 && t == 0) offs[N_NODES] = N_EDGES;
}

__global__ void k_scatter(const int* __restrict__ src, const int* __restrict__ dst,
                          int* __restrict__ cursor, int* __restrict__ ssrc) {
  int gid = blockIdx.x * blockDim.x + threadIdx.x;
  if (gid < N_EDGES) {
    int d = dst[gid];
    int pos = atomicAdd(&cursor[d], 1);
    ssrc[pos] = src[gid];
  }
}

// ---------------- per-node softmax + weighted aggregation ----------------
// one 64-lane wave per node; lane handles features 2*lane, 2*lane+1
__global__ __launch_bounds__(256) void k_agg(const int* __restrict__ offs,
                                             const int* __restrict__ ssrc,
                                             const float* __restrict__ ft,
                                             const float* __restrict__ el,
                                             const float* __restrict__ er,
                                             float* __restrict__ out) {
  int wave = threadIdx.x >> 6;
  int lane = threadIdx.x & 63;
  int n = blockIdx.x * 4 + wave;
  if (n >= N_NODES) return;
  int start = offs[n], end = offs[n + 1];
  int f0 = lane * 2;
  int hh = lane >> 4;
  float2 acc = {0.f, 0.f};
  if (start < end) {
    float4 er4 = *(const float4*)&er[n * 4];
    float erh[4] = {er4.x, er4.y, er4.z, er4.w};
    float m[4] = {-INFINITY, -INFINITY, -INFINITY, -INFINITY};
    for (int c = start; c < end; c += 64) {
      int i = c + lane;
      bool valid = i < end;
      int s = valid ? ssrc[i] : 0;
      float4 e4 = *(const float4*)&el[s * 4];
      float ee[4] = {e4.x, e4.y, e4.z, e4.w};
      #pragma unroll
      for (int h = 0; h < 4; ++h) {
        float v = ee[h] + erh[h];
        v = v > 0.f ? v : NEG_SLOPE * v;
        if (!valid) v = -INFINITY;
        m[h] = fmaxf(m[h], v);
      }
    }
    #pragma unroll
    for (int h = 0; h < 4; ++h)
      #pragma unroll
      for (int o = 32; o > 0; o >>= 1) m[h] = fmaxf(m[h], __shfl_xor(m[h], o));
    float den[4] = {0.f, 0.f, 0.f, 0.f};
    for (int c = start; c < end; c += 64) {
      int i = c + lane;
      bool valid = i < end;
      int s = valid ? ssrc[i] : 0;
      float4 e4 = *(const float4*)&el[s * 4];
      float ee[4] = {e4.x, e4.y, e4.z, e4.w};
      #pragma unroll
      for (int h = 0; h < 4; ++h) {
        float v = ee[h] + erh[h];
        v = v > 0.f ? v : NEG_SLOPE * v;
        den[h] += valid ? __expf(v - m[h]) : 0.f;
      }
    }
    #pragma unroll
    for (int h = 0; h < 4; ++h)
      #pragma unroll
      for (int o = 32; o > 0; o >>= 1) den[h] += __shfl_xor(den[h], o);
    float invd = 1.f / den[hh];
    for (int c = start; c < end; c += 64) {
      int i = c + lane;
      bool valid = i < end;
      int s = valid ? ssrc[i] : 0;
      float4 e4 = *(const float4*)&el[s * 4];
      float ee[4] = {e4.x, e4.y, e4.z, e4.w};
      float ex[4];
      #pragma unroll
      for (int h = 0; h < 4; ++h) {
        float v = ee[h] + erh[h];
        v = v > 0.f ? v : NEG_SLOPE * v;
        ex[h] = __expf(v - m[h]);
      }
      int cnt2 = min(64, end - c);
      for (int j = 0; j < cnt2; ++j) {
        int sj = __shfl(s, j);
        float a0 = __shfl(ex[0], j);
        float a1 = __shfl(ex[1], j);
        float a2 = __shfl(ex[2], j);
        float a3 = __shfl(ex[3], j);
        float ah = hh == 0 ? a0 : (hh == 1 ? a1 : (hh == 2 ? a2 : a3));
        ah *= invd;
        float2 v = *(const float2*)&ft[(size_t)sj * D_HID + f0];
        acc.x += ah * v.x;
        acc.y += ah * v.y;
      }
    }
  }
  *(float2*)&out[(size_t)n * D_HID + f0] = acc;
}

extern "C" void kernel_launch(void* const* d_in, const int* in_sizes, int n_in,
                              void* d_out, int out_size, void* d_ws, size_t ws_size,
                              hipStream_t stream) {
  const float* x      = (const float*)d_in[0];
  const float* fc_w   = (const float*)d_in[1];
  const float* attn_l = (const float*)d_in[2];
  const float* attn_r = (const float*)d_in[3];
  const int*   src    = (const int*)d_in[4];
  const int*   dst    = (const int*)d_in[5];
  float* out = (float*)d_out;

  char* wsp = (char*)d_ws;
  size_t off = 0;
  auto alloc = [&](size_t bytes) {
    void* p = wsp + off;
    off = (off + bytes + 255) & ~(size_t)255;
    return p;
  };
  float* ft     = (float*)alloc((size_t)N_NODES * D_HID * 4);
  float* el     = (float*)alloc((size_t)N_NODES * 4 * 4);
  float* er     = (float*)alloc((size_t)N_NODES * 4 * 4);
  int*   cnt    = (int*)alloc((size_t)N_NODES * 4);
  int*   offs   = (int*)alloc((size_t)(N_NODES + 1) * 4);
  int*   cursor = (int*)alloc((size_t)N_NODES * 4);
  int*   ssrc   = (int*)alloc((size_t)N_EDGES * 4);
  int*   part   = (int*)alloc((size_t)N_SCAN_BLOCKS * 4);
  int*   epart  = (int*)alloc((size_t)128 * 4);

  hipMemsetAsync(cnt, 0, (size_t)N_NODES * 4, stream);
  k_gemm<<<(N_NODES + 63) / 64, 256, 0, stream>>>(x, fc_w, ft);
  k_eler<<<(N_NODES * N_HEADS + 255) / 256, 256, 0, stream>>>(ft, attn_l, attn_r, el, er);
  k_hist<<<(N_EDGES + 255) / 256, 256, 0, stream>>>(dst, cnt);
  k_partial<<<N_SCAN_BLOCKS, 256, 0, stream>>>(cnt, part);
  k_scanpart<<<1, 128, 0, stream>>>(part, epart);
  k_offsets<<<N_SCAN_BLOCKS, 256, 0, stream>>>(cnt, epart, offs, cursor);
  k_scatter<<<(N_EDGES + 255) / 256, 256, 0, stream>>>(src, dst, cursor, ssrc);
  k_agg<<<(N_NODES + 3) / 4, 256, 0, stream>>>(offs, ssrc, ft, el, er, out);
}

// Round 3
// 487.550 us; speedup vs baseline: 1.7417x; 1.2363x over previous
//
#include <hip/hip_runtime.h>
#include <math.h>

#define N_NODES 100000
#define N_EDGES 1600000
#define D_IN 256
#define N_HEADS 4
#define D_OUT 32
#define D_HID 128   // N_HEADS*D_OUT
#define NEG_SLOPE 0.2f

#define SCAN_CHUNK 1024
#define N_SCAN_BLOCKS ((N_NODES + SCAN_CHUNK - 1) / SCAN_CHUNK)  // 98

typedef __attribute__((ext_vector_type(8))) short bf16x8;
typedef __attribute__((ext_vector_type(4))) float f32x4;

static __device__ __forceinline__ unsigned short f2bf(float f) {
  union { float f; unsigned u; } c; c.f = f;
  unsigned r = c.u + 0x7FFFu + ((c.u >> 16) & 1u);  // RNE
  return (unsigned short)(r >> 16);
}
static __device__ __forceinline__ float bfu_lo(unsigned u) {
  union { unsigned u; float f; } c; c.u = u << 16; return c.f;
}
static __device__ __forceinline__ float bfu_hi(unsigned u) {
  union { unsigned u; float f; } c; c.u = u & 0xFFFF0000u; return c.f;
}

// ---------------- GEMM: ftb[N,128](bf16) = x[N,256] @ w[128,256]^T ----------
// MFMA 16x16x32 bf16. BM=128, BN=128, BK=32, 256 threads = 4 waves (2x2 of 64x64).
#define LDA 40  // padded LDS row stride in bf16 elems (80 B, 16B-aligned frags)
__global__ __launch_bounds__(256) void k_gemm(const float* __restrict__ x,
                                              const float* __restrict__ w,
                                              unsigned short* __restrict__ ftb) {
  __shared__ short As[128 * LDA];
  __shared__ short Bs[128 * LDA];
  int t = threadIdx.x;
  int wave = t >> 6, lane = t & 63;
  int quad = lane >> 4, l16 = lane & 15;
  int rowBase = blockIdx.x * 128;
  int wm = (wave >> 1) * 64, wn = (wave & 1) * 64;
  f32x4 acc[4][4];
  #pragma unroll
  for (int mt = 0; mt < 4; ++mt)
    #pragma unroll
    for (int nt = 0; nt < 4; ++nt) {
      acc[mt][nt][0] = 0.f; acc[mt][nt][1] = 0.f;
      acc[mt][nt][2] = 0.f; acc[mt][nt][3] = 0.f;
    }

  for (int kb = 0; kb < D_IN; kb += 32) {
    // stage A tile: 128 rows x 32 k, fp32 -> bf16
    #pragma unroll
    for (int p = 0; p < 4; ++p) {
      int idx = p * 256 + t;       // 0..1023
      int r = idx >> 3;            // 0..127
      int kq = (idx & 7) * 4;      // 0,4,...,28
      int row = rowBase + r;
      float4 v = make_float4(0.f, 0.f, 0.f, 0.f);
      if (row < N_NODES) v = *(const float4*)&x[(size_t)row * D_IN + kb + kq];
      short* d = &As[r * LDA + kq];
      d[0] = (short)f2bf(v.x); d[1] = (short)f2bf(v.y);
      d[2] = (short)f2bf(v.z); d[3] = (short)f2bf(v.w);
    }
    // stage B tile: w[128][kb..kb+31] as [n][k]
    #pragma unroll
    for (int p = 0; p < 4; ++p) {
      int idx = p * 256 + t;
      int r = idx >> 3;
      int kq = (idx & 7) * 4;
      float4 v = *(const float4*)&w[(size_t)r * D_IN + kb + kq];
      short* d = &Bs[r * LDA + kq];
      d[0] = (short)f2bf(v.x); d[1] = (short)f2bf(v.y);
      d[2] = (short)f2bf(v.z); d[3] = (short)f2bf(v.w);
    }
    __syncthreads();
    bf16x8 af[4], bfr[4];
    #pragma unroll
    for (int mt = 0; mt < 4; ++mt)
      af[mt] = *(const bf16x8*)&As[(wm + mt * 16 + l16) * LDA + quad * 8];
    #pragma unroll
    for (int nt = 0; nt < 4; ++nt)
      bfr[nt] = *(const bf16x8*)&Bs[(wn + nt * 16 + l16) * LDA + quad * 8];
    #pragma unroll
    for (int mt = 0; mt < 4; ++mt)
      #pragma unroll
      for (int nt = 0; nt < 4; ++nt)
        acc[mt][nt] = __builtin_amdgcn_mfma_f32_16x16x32_bf16(af[mt], bfr[nt], acc[mt][nt], 0, 0, 0);
    __syncthreads();
  }
  // epilogue: C[row][col], row = quad*4+reg, col = lane&15; store bf16
  #pragma unroll
  for (int mt = 0; mt < 4; ++mt) {
    #pragma unroll
    for (int nt = 0; nt < 4; ++nt) {
      int col = wn + nt * 16 + l16;
      #pragma unroll
      for (int r = 0; r < 4; ++r) {
        int row = rowBase + wm + mt * 16 + quad * 4 + r;
        if (row < N_NODES)
          ftb[(size_t)row * D_HID + col] = f2bf(acc[mt][nt][r]);
      }
    }
  }
}

// ---------------- per-node attention logits el,er [N,4] ----------------
__global__ void k_eler(const unsigned short* __restrict__ ftb,
                       const float* __restrict__ al,
                       const float* __restrict__ ar,
                       float* __restrict__ el, float* __restrict__ er) {
  int gid = blockIdx.x * blockDim.x + threadIdx.x;
  if (gid >= N_NODES * N_HEADS) return;
  int n = gid >> 2, h = gid & 3;
  const unsigned* f = (const unsigned*)&ftb[(size_t)n * D_HID + h * D_OUT];
  const float* alh = &al[h * D_OUT];
  const float* arh = &ar[h * D_OUT];
  float sl = 0.f, sr = 0.f;
  #pragma unroll
  for (int i = 0; i < 16; ++i) {
    unsigned u = f[i];
    float lo = bfu_lo(u), hi = bfu_hi(u);
    sl += lo * alh[2 * i] + hi * alh[2 * i + 1];
    sr += lo * arh[2 * i] + hi * arh[2 * i + 1];
  }
  el[gid] = sl;
  er[gid] = sr;
}

// ---------------- counting sort by dst ----------------
__global__ void k_hist(const int* __restrict__ dst, int* __restrict__ cnt) {
  int gid = blockIdx.x * blockDim.x + threadIdx.x;
  if (gid < N_EDGES) atomicAdd(&cnt[dst[gid]], 1);
}

__global__ __launch_bounds__(256) void k_partial(const int* __restrict__ cnt,
                                                 int* __restrict__ part) {
  __shared__ int red[4];
  int b = blockIdx.x, t = threadIdx.x;
  int idx = b * SCAN_CHUNK + t * 4;
  int a0 = 0, a1 = 0, a2 = 0, a3 = 0;
  if (idx + 3 < N_NODES) {
    int4 v = *(const int4*)&cnt[idx];
    a0 = v.x; a1 = v.y; a2 = v.z; a3 = v.w;
  } else {
    if (idx + 0 < N_NODES) a0 = cnt[idx + 0];
    if (idx + 1 < N_NODES) a1 = cnt[idx + 1];
    if (idx + 2 < N_NODES) a2 = cnt[idx + 2];
    if (idx + 3 < N_NODES) a3 = cnt[idx + 3];
  }
  int s = a0 + a1 + a2 + a3;
  #pragma unroll
  for (int o = 32; o > 0; o >>= 1) s += __shfl_xor(s, o);
  if ((t & 63) == 0) red[t >> 6] = s;
  __syncthreads();
  if (t == 0) part[b] = red[0] + red[1] + red[2] + red[3];
}

__global__ __launch_bounds__(128) void k_scanpart(const int* __restrict__ part,
                                                  int* __restrict__ epart) {
  __shared__ int ss[128];
  int t = threadIdx.x;
  int v = (t < N_SCAN_BLOCKS) ? part[t] : 0;
  ss[t] = v;
  __syncthreads();
  #pragma unroll
  for (int d = 1; d < 128; d <<= 1) {
    int u = (t >= d) ? ss[t - d] : 0;
    __syncthreads();
    ss[t] += u;
    __syncthreads();
  }
  epart[t] = (t == 0) ? 0 : ss[t - 1];
}

__global__ __launch_bounds__(256) void k_offsets(const int* __restrict__ cnt,
                                                 const int* __restrict__ epart,
                                                 int* __restrict__ offs,
                                                 int* __restrict__ cursor) {
  __shared__ int ss[256];
  int b = blockIdx.x, t = threadIdx.x;
  int idx = b * SCAN_CHUNK + t * 4;
  int a0 = 0, a1 = 0, a2 = 0, a3 = 0;
  if (idx + 3 < N_NODES) {
    int4 v = *(const int4*)&cnt[idx];
    a0 = v.x; a1 = v.y; a2 = v.z; a3 = v.w;
  } else {
    if (idx + 0 < N_NODES) a0 = cnt[idx + 0];
    if (idx + 1 < N_NODES) a1 = cnt[idx + 1];
    if (idx + 2 < N_NODES) a2 = cnt[idx + 2];
    if (idx + 3 < N_NODES) a3 = cnt[idx + 3];
  }
  int tsum = a0 + a1 + a2 + a3;
  ss[t] = tsum;
  __syncthreads();
  #pragma unroll
  for (int d = 1; d < 256; d <<= 1) {
    int u = (t >= d) ? ss[t - d] : 0;
    __syncthreads();
    ss[t] += u;
    __syncthreads();
  }
  int run = epart[b] + ((t == 0) ? 0 : ss[t - 1]);
  int o0 = run; run += a0;
  int o1 = run; run += a1;
  int o2 = run; run += a2;
  int o3 = run;
  if (idx + 3 < N_NODES) {
    int4 ov = make_int4(o0, o1, o2, o3);
    *(int4*)&offs[idx] = ov;
    *(int4*)&cursor[idx] = ov;
  } else {
    if (idx + 0 < N_NODES) { offs[idx + 0] = o0; cursor[idx + 0] = o0; }
    if (idx + 1 < N_NODES) { offs[idx + 1] = o1; cursor[idx + 1] = o1; }
    if (idx + 2 < N_NODES) { offs[idx + 2] = o2; cursor[idx + 2] = o2; }
  }
  if (b == 0 && t == 0) offs[N_NODES] = N_EDGES;
}

__global__ void k_scatter(const int* __restrict__ src, const int* __restrict__ dst,
                          int* __restrict__ cursor, int* __restrict__ ssrc) {
  int gid = blockIdx.x * blockDim.x + threadIdx.x;
  if (gid < N_EDGES) {
    int d = dst[gid];
    int pos = atomicAdd(&cursor[d], 1);
    ssrc[pos] = src[gid];
  }
}

// ---------------- per-node softmax + weighted aggregation (bf16 ft) --------
// one 64-lane wave per node; lane handles features 2*lane, 2*lane+1
__global__ __launch_bounds__(256) void k_agg(const int* __restrict__ offs,
                                             const int* __restrict__ ssrc,
                                             const unsigned short* __restrict__ ftb,
                                             const float* __restrict__ el,
                                             const float* __restrict__ er,
                                             float* __restrict__ out) {
  __shared__ int   lds_s[4][64];
  __shared__ float lds_a[4][64][4];
  int wave = threadIdx.x >> 6;
  int lane = threadIdx.x & 63;
  int n = blockIdx.x * 4 + wave;
  if (n >= N_NODES) return;
  int start = offs[n], end = offs[n + 1];
  int deg = end - start;
  int f0 = lane * 2;
  int hh = lane >> 4;
  float2 acc = {0.f, 0.f};

  if (deg > 0 && deg <= 64) {
    // ---- fast path: single chunk, single load of edge data ----
    float4 er4 = *(const float4*)&er[n * 4];
    bool valid = lane < deg;
    int s = valid ? ssrc[start + lane] : 0;
    float4 e4 = *(const float4*)&el[s * 4];
    float v[4] = {e4.x + er4.x, e4.y + er4.y, e4.z + er4.z, e4.w + er4.w};
    float m[4], ex[4], den[4];
    #pragma unroll
    for (int h = 0; h < 4; ++h) {
      v[h] = v[h] > 0.f ? v[h] : NEG_SLOPE * v[h];
      m[h] = valid ? v[h] : -INFINITY;
    }
    #pragma unroll
    for (int h = 0; h < 4; ++h)
      #pragma unroll
      for (int o = 32; o > 0; o >>= 1) m[h] = fmaxf(m[h], __shfl_xor(m[h], o));
    #pragma unroll
    for (int h = 0; h < 4; ++h) {
      ex[h] = valid ? __expf(v[h] - m[h]) : 0.f;
      den[h] = ex[h];
    }
    #pragma unroll
    for (int h = 0; h < 4; ++h)
      #pragma unroll
      for (int o = 32; o > 0; o >>= 1) den[h] += __shfl_xor(den[h], o);
    float4 a4 = make_float4(ex[0] / den[0], ex[1] / den[1], ex[2] / den[2], ex[3] / den[3]);
    lds_s[wave][lane] = s;
    *(float4*)&lds_a[wave][lane][0] = a4;
    __builtin_amdgcn_wave_barrier();
    for (int j = 0; j < deg; ++j) {
      int sj = lds_s[wave][j];
      float a = lds_a[wave][j][hh];
      unsigned u = *(const unsigned*)&ftb[(size_t)sj * D_HID + f0];
      acc.x += a * bfu_lo(u);
      acc.y += a * bfu_hi(u);
    }
  } else if (deg > 64) {
    // ---- fallback: chunked 3-pass (rare; correctness only) ----
    float4 er4 = *(const float4*)&er[n * 4];
    float erh[4] = {er4.x, er4.y, er4.z, er4.w};
    float m[4] = {-INFINITY, -INFINITY, -INFINITY, -INFINITY};
    for (int c = start; c < end; c += 64) {
      int i = c + lane;
      bool valid = i < end;
      int s = valid ? ssrc[i] : 0;
      float4 e4 = *(const float4*)&el[s * 4];
      float ee[4] = {e4.x, e4.y, e4.z, e4.w};
      #pragma unroll
      for (int h = 0; h < 4; ++h) {
        float v = ee[h] + erh[h];
        v = v > 0.f ? v : NEG_SLOPE * v;
        if (!valid) v = -INFINITY;
        m[h] = fmaxf(m[h], v);
      }
    }
    #pragma unroll
    for (int h = 0; h < 4; ++h)
      #pragma unroll
      for (int o = 32; o > 0; o >>= 1) m[h] = fmaxf(m[h], __shfl_xor(m[h], o));
    float den[4] = {0.f, 0.f, 0.f, 0.f};
    for (int c = start; c < end; c += 64) {
      int i = c + lane;
      bool valid = i < end;
      int s = valid ? ssrc[i] : 0;
      float4 e4 = *(const float4*)&el[s * 4];
      float ee[4] = {e4.x, e4.y, e4.z, e4.w};
      #pragma unroll
      for (int h = 0; h < 4; ++h) {
        float v = ee[h] + erh[h];
        v = v > 0.f ? v : NEG_SLOPE * v;
        den[h] += valid ? __expf(v - m[h]) : 0.f;
      }
    }
    #pragma unroll
    for (int h = 0; h < 4; ++h)
      #pragma unroll
      for (int o = 32; o > 0; o >>= 1) den[h] += __shfl_xor(den[h], o);
    float invd = 1.f / den[hh];
    for (int c = start; c < end; c += 64) {
      int i = c + lane;
      bool valid = i < end;
      int s = valid ? ssrc[i] : 0;
      float4 e4 = *(const float4*)&el[s * 4];
      float ee[4] = {e4.x, e4.y, e4.z, e4.w};
      float ex[4];
      #pragma unroll
      for (int h = 0; h < 4; ++h) {
        float v = ee[h] + erh[h];
        v = v > 0.f ? v : NEG_SLOPE * v;
        ex[h] = __expf(v - m[h]);
      }
      int cnt2 = min(64, end - c);
      for (int j = 0; j < cnt2; ++j) {
        int sj = __shfl(s, j);
        float a0 = __shfl(ex[0], j);
        float a1 = __shfl(ex[1], j);
        float a2 = __shfl(ex[2], j);
        float a3 = __shfl(ex[3], j);
        float ah = hh == 0 ? a0 : (hh == 1 ? a1 : (hh == 2 ? a2 : a3));
        ah *= invd;
        unsigned u = *(const unsigned*)&ftb[(size_t)sj * D_HID + f0];
        acc.x += ah * bfu_lo(u);
        acc.y += ah * bfu_hi(u);
      }
    }
  }
  *(float2*)&out[(size_t)n * D_HID + f0] = acc;
}

extern "C" void kernel_launch(void* const* d_in, const int* in_sizes, int n_in,
                              void* d_out, int out_size, void* d_ws, size_t ws_size,
                              hipStream_t stream) {
  const float* x      = (const float*)d_in[0];
  const float* fc_w   = (const float*)d_in[1];
  const float* attn_l = (const float*)d_in[2];
  const float* attn_r = (const float*)d_in[3];
  const int*   src    = (const int*)d_in[4];
  const int*   dst    = (const int*)d_in[5];
  float* out = (float*)d_out;

  char* wsp = (char*)d_ws;
  size_t off = 0;
  auto alloc = [&](size_t bytes) {
    void* p = wsp + off;
    off = (off + bytes + 255) & ~(size_t)255;
    return p;
  };
  unsigned short* ftb = (unsigned short*)alloc((size_t)N_NODES * D_HID * 2);
  float* el     = (float*)alloc((size_t)N_NODES * 4 * 4);
  float* er     = (float*)alloc((size_t)N_NODES * 4 * 4);
  int*   cnt    = (int*)alloc((size_t)N_NODES * 4);
  int*   offs   = (int*)alloc((size_t)(N_NODES + 1) * 4);
  int*   cursor = (int*)alloc((size_t)N_NODES * 4);
  int*   ssrc   = (int*)alloc((size_t)N_EDGES * 4);
  int*   part   = (int*)alloc((size_t)N_SCAN_BLOCKS * 4);
  int*   epart  = (int*)alloc((size_t)128 * 4);

  hipMemsetAsync(cnt, 0, (size_t)N_NODES * 4, stream);
  k_gemm<<<(N_NODES + 127) / 128, 256, 0, stream>>>(x, fc_w, ftb);
  k_eler<<<(N_NODES * N_HEADS + 255) / 256, 256, 0, stream>>>(ftb, attn_l, attn_r, el, er);
  k_hist<<<(N_EDGES + 255) / 256, 256, 0, stream>>>(dst, cnt);
  k_partial<<<N_SCAN_BLOCKS, 256, 0, stream>>>(cnt, part);
  k_scanpart<<<1, 128, 0, stream>>>(part, epart);
  k_offsets<<<N_SCAN_BLOCKS, 256, 0, stream>>>(cnt, epart, offs, cursor);
  k_scatter<<<(N_EDGES + 255) / 256, 256, 0, stream>>>(src, dst, cursor, ssrc);
  k_agg<<<(N_NODES + 3) / 4, 256, 0, stream>>>(offs, ssrc, ftb, el, er, out);
}

// Round 4
// 355.763 us; speedup vs baseline: 2.3869x; 1.3704x over previous
//
#include <hip/hip_runtime.h>
#include <math.h>

#define N_NODES 100000
#define N_EDGES 1600000
#define D_IN 256
#define N_HEADS 4
#define D_OUT 32
#define D_HID 128   // N_HEADS*D_OUT
#define NEG_SLOPE 0.2f

// bucketed sort params
#define BUCKET_SHIFT 8
#define BUCKET_NODES 256
#define NB ((N_NODES + BUCKET_NODES - 1) / BUCKET_NODES)  // 391
#define CAP 6144      // >> mean 4096 + 32 sigma
#define TILE 8192
#define N_TILES ((N_EDGES + TILE - 1) / TILE)             // 196

typedef __attribute__((ext_vector_type(8))) short bf16x8;
typedef __attribute__((ext_vector_type(4))) float f32x4;

static __device__ __forceinline__ unsigned short f2bf(float f) {
  union { float f; unsigned u; } c; c.f = f;
  unsigned r = c.u + 0x7FFFu + ((c.u >> 16) & 1u);  // RNE
  return (unsigned short)(r >> 16);
}
static __device__ __forceinline__ float bfu_lo(unsigned u) {
  union { unsigned u; float f; } c; c.u = u << 16; return c.f;
}
static __device__ __forceinline__ float bfu_hi(unsigned u) {
  union { unsigned u; float f; } c; c.u = u & 0xFFFF0000u; return c.f;
}

// ---------------- GEMM: ftb[N,128](bf16) = x[N,256] @ w[128,256]^T ----------
#define LDA 40  // padded LDS row stride in bf16 elems
__global__ __launch_bounds__(256) void k_gemm(const float* __restrict__ x,
                                              const float* __restrict__ w,
                                              unsigned short* __restrict__ ftb) {
  __shared__ short As[128 * LDA];
  __shared__ short Bs[128 * LDA];
  int t = threadIdx.x;
  int wave = t >> 6, lane = t & 63;
  int quad = lane >> 4, l16 = lane & 15;
  int rowBase = blockIdx.x * 128;
  int wm = (wave >> 1) * 64, wn = (wave & 1) * 64;
  f32x4 acc[4][4];
  #pragma unroll
  for (int mt = 0; mt < 4; ++mt)
    #pragma unroll
    for (int nt = 0; nt < 4; ++nt) {
      acc[mt][nt][0] = 0.f; acc[mt][nt][1] = 0.f;
      acc[mt][nt][2] = 0.f; acc[mt][nt][3] = 0.f;
    }

  for (int kb = 0; kb < D_IN; kb += 32) {
    #pragma unroll
    for (int p = 0; p < 4; ++p) {
      int idx = p * 256 + t;
      int r = idx >> 3;
      int kq = (idx & 7) * 4;
      int row = rowBase + r;
      float4 v = make_float4(0.f, 0.f, 0.f, 0.f);
      if (row < N_NODES) v = *(const float4*)&x[(size_t)row * D_IN + kb + kq];
      short* d = &As[r * LDA + kq];
      d[0] = (short)f2bf(v.x); d[1] = (short)f2bf(v.y);
      d[2] = (short)f2bf(v.z); d[3] = (short)f2bf(v.w);
    }
    #pragma unroll
    for (int p = 0; p < 4; ++p) {
      int idx = p * 256 + t;
      int r = idx >> 3;
      int kq = (idx & 7) * 4;
      float4 v = *(const float4*)&w[(size_t)r * D_IN + kb + kq];
      short* d = &Bs[r * LDA + kq];
      d[0] = (short)f2bf(v.x); d[1] = (short)f2bf(v.y);
      d[2] = (short)f2bf(v.z); d[3] = (short)f2bf(v.w);
    }
    __syncthreads();
    bf16x8 af[4], bfr[4];
    #pragma unroll
    for (int mt = 0; mt < 4; ++mt)
      af[mt] = *(const bf16x8*)&As[(wm + mt * 16 + l16) * LDA + quad * 8];
    #pragma unroll
    for (int nt = 0; nt < 4; ++nt)
      bfr[nt] = *(const bf16x8*)&Bs[(wn + nt * 16 + l16) * LDA + quad * 8];
    #pragma unroll
    for (int mt = 0; mt < 4; ++mt)
      #pragma unroll
      for (int nt = 0; nt < 4; ++nt)
        acc[mt][nt] = __builtin_amdgcn_mfma_f32_16x16x32_bf16(af[mt], bfr[nt], acc[mt][nt], 0, 0, 0);
    __syncthreads();
  }
  #pragma unroll
  for (int mt = 0; mt < 4; ++mt) {
    #pragma unroll
    for (int nt = 0; nt < 4; ++nt) {
      int col = wn + nt * 16 + l16;
      #pragma unroll
      for (int r = 0; r < 4; ++r) {
        int row = rowBase + wm + mt * 16 + quad * 4 + r;
        if (row < N_NODES)
          ftb[(size_t)row * D_HID + col] = f2bf(acc[mt][nt][r]);
      }
    }
  }
}

// ---------------- per-node attention logits el,er [N,4] ----------------
__global__ void k_eler(const unsigned short* __restrict__ ftb,
                       const float* __restrict__ al,
                       const float* __restrict__ ar,
                       float* __restrict__ el, float* __restrict__ er) {
  int gid = blockIdx.x * blockDim.x + threadIdx.x;
  if (gid >= N_NODES * N_HEADS) return;
  int n = gid >> 2, h = gid & 3;
  const unsigned* f = (const unsigned*)&ftb[(size_t)n * D_HID + h * D_OUT];
  const float* alh = &al[h * D_OUT];
  const float* arh = &ar[h * D_OUT];
  float sl = 0.f, sr = 0.f;
  #pragma unroll
  for (int i = 0; i < 16; ++i) {
    unsigned u = f[i];
    float lo = bfu_lo(u), hi = bfu_hi(u);
    sl += lo * alh[2 * i] + hi * alh[2 * i + 1];
    sr += lo * arh[2 * i] + hi * arh[2 * i + 1];
  }
  el[gid] = sl;
  er[gid] = sr;
}

// ---------------- phase 1: bucket edges by dst>>8, packed (src<<8)|dlocal ---
__global__ __launch_bounds__(256) void k_bucket(const int* __restrict__ src,
                                                const int* __restrict__ dst,
                                                int* __restrict__ gfill,
                                                unsigned* __restrict__ pairs) {
  __shared__ int bcnt[NB];
  __shared__ int brsv[NB];
  __shared__ int brank[NB];
  int t = threadIdx.x;
  for (int tile = blockIdx.x; tile < N_TILES; tile += gridDim.x) {
    int e0 = tile * TILE;
    int e1 = min(e0 + TILE, N_EDGES);
    for (int i = t; i < NB; i += 256) { bcnt[i] = 0; brank[i] = 0; }
    __syncthreads();
    for (int i = e0 + t; i < e1; i += 256)
      atomicAdd(&bcnt[dst[i] >> BUCKET_SHIFT], 1);
    __syncthreads();
    for (int i = t; i < NB; i += 256) {
      int c = bcnt[i];
      brsv[i] = (c > 0) ? atomicAdd(&gfill[i], c) : 0;
    }
    __syncthreads();
    for (int i = e0 + t; i < e1; i += 256) {
      int d = dst[i];
      int s = src[i];
      int b = d >> BUCKET_SHIFT;
      int r = brsv[b] + atomicAdd(&brank[b], 1);
      if (r < CAP)
        pairs[(size_t)b * CAP + r] = ((unsigned)s << 8) | (unsigned)(d & (BUCKET_NODES - 1));
    }
    __syncthreads();
  }
}

// ---------------- phase 2: exclusive scan of bucket fills -------------------
__global__ __launch_bounds__(512) void k_scanbuckets(const int* __restrict__ gfill,
                                                     int* __restrict__ bbase,
                                                     int* __restrict__ offs) {
  __shared__ int ss[512];
  int t = threadIdx.x;
  int v = (t < NB) ? gfill[t] : 0;
  ss[t] = v;
  __syncthreads();
  #pragma unroll
  for (int d = 1; d < 512; d <<= 1) {
    int u = (t >= d) ? ss[t - d] : 0;
    __syncthreads();
    ss[t] += u;
    __syncthreads();
  }
  if (t < NB) bbase[t] = (t == 0) ? 0 : ss[t - 1];
  if (t == 0) offs[N_NODES] = N_EDGES;
}

// ---------------- phase 3: per-bucket counting sort -> offs, ssrc -----------
__global__ __launch_bounds__(256) void k_localsort(const unsigned* __restrict__ pairs,
                                                   const int* __restrict__ gfill,
                                                   const int* __restrict__ bbase,
                                                   int* __restrict__ offs,
                                                   int* __restrict__ ssrc) {
  __shared__ int cnt_l[256];
  __shared__ int ss[256];
  __shared__ int cur_l[256];
  int b = blockIdx.x, t = threadIdx.x;
  int E = min(gfill[b], CAP);
  int base = bbase[b];
  const unsigned* pb = &pairs[(size_t)b * CAP];
  cnt_l[t] = 0;
  __syncthreads();
  for (int i = t; i < E; i += 256)
    atomicAdd(&cnt_l[pb[i] & (BUCKET_NODES - 1)], 1);
  __syncthreads();
  int v = cnt_l[t];
  ss[t] = v;
  __syncthreads();
  #pragma unroll
  for (int d = 1; d < 256; d <<= 1) {
    int u = (t >= d) ? ss[t - d] : 0;
    __syncthreads();
    ss[t] += u;
    __syncthreads();
  }
  int pre = (t == 0) ? 0 : ss[t - 1];
  int node = b * BUCKET_NODES + t;
  if (node < N_NODES) offs[node] = base + pre;
  cur_l[t] = pre;
  __syncthreads();
  for (int i = t; i < E; i += 256) {
    unsigned p = pb[i];
    int pos = atomicAdd(&cur_l[p & (BUCKET_NODES - 1)], 1);
    ssrc[base + pos] = (int)(p >> 8);
  }
}

// ---------------- per-node softmax + weighted aggregation (bf16 ft) --------
__global__ __launch_bounds__(256) void k_agg(const int* __restrict__ offs,
                                             const int* __restrict__ ssrc,
                                             const unsigned short* __restrict__ ftb,
                                             const float* __restrict__ el,
                                             const float* __restrict__ er,
                                             float* __restrict__ out) {
  __shared__ int   lds_s[4][64];
  __shared__ float lds_a[4][64][4];
  int wave = threadIdx.x >> 6;
  int lane = threadIdx.x & 63;
  int n = blockIdx.x * 4 + wave;
  if (n >= N_NODES) return;
  int start = offs[n], end = offs[n + 1];
  int deg = end - start;
  int f0 = lane * 2;
  int hh = lane >> 4;
  float2 acc = {0.f, 0.f};

  if (deg > 0 && deg <= 64) {
    float4 er4 = *(const float4*)&er[n * 4];
    bool valid = lane < deg;
    int s = valid ? ssrc[start + lane] : 0;
    float4 e4 = *(const float4*)&el[s * 4];
    float v[4] = {e4.x + er4.x, e4.y + er4.y, e4.z + er4.z, e4.w + er4.w};
    float m[4], ex[4], den[4];
    #pragma unroll
    for (int h = 0; h < 4; ++h) {
      v[h] = v[h] > 0.f ? v[h] : NEG_SLOPE * v[h];
      m[h] = valid ? v[h] : -INFINITY;
    }
    #pragma unroll
    for (int h = 0; h < 4; ++h)
      #pragma unroll
      for (int o = 32; o > 0; o >>= 1) m[h] = fmaxf(m[h], __shfl_xor(m[h], o));
    #pragma unroll
    for (int h = 0; h < 4; ++h) {
      ex[h] = valid ? __expf(v[h] - m[h]) : 0.f;
      den[h] = ex[h];
    }
    #pragma unroll
    for (int h = 0; h < 4; ++h)
      #pragma unroll
      for (int o = 32; o > 0; o >>= 1) den[h] += __shfl_xor(den[h], o);
    float4 a4 = make_float4(ex[0] / den[0], ex[1] / den[1], ex[2] / den[2], ex[3] / den[3]);
    lds_s[wave][lane] = s;
    *(float4*)&lds_a[wave][lane][0] = a4;
    __builtin_amdgcn_wave_barrier();
    for (int j = 0; j < deg; ++j) {
      int sj = lds_s[wave][j];
      float a = lds_a[wave][j][hh];
      unsigned u = *(const unsigned*)&ftb[(size_t)sj * D_HID + f0];
      acc.x += a * bfu_lo(u);
      acc.y += a * bfu_hi(u);
    }
  } else if (deg > 64) {
    float4 er4 = *(const float4*)&er[n * 4];
    float erh[4] = {er4.x, er4.y, er4.z, er4.w};
    float m[4] = {-INFINITY, -INFINITY, -INFINITY, -INFINITY};
    for (int c = start; c < end; c += 64) {
      int i = c + lane;
      bool valid = i < end;
      int s = valid ? ssrc[i] : 0;
      float4 e4 = *(const float4*)&el[s * 4];
      float ee[4] = {e4.x, e4.y, e4.z, e4.w};
      #pragma unroll
      for (int h = 0; h < 4; ++h) {
        float v = ee[h] + erh[h];
        v = v > 0.f ? v : NEG_SLOPE * v;
        if (!valid) v = -INFINITY;
        m[h] = fmaxf(m[h], v);
      }
    }
    #pragma unroll
    for (int h = 0; h < 4; ++h)
      #pragma unroll
      for (int o = 32; o > 0; o >>= 1) m[h] = fmaxf(m[h], __shfl_xor(m[h], o));
    float den[4] = {0.f, 0.f, 0.f, 0.f};
    for (int c = start; c < end; c += 64) {
      int i = c + lane;
      bool valid = i < end;
      int s = valid ? ssrc[i] : 0;
      float4 e4 = *(const float4*)&el[s * 4];
      float ee[4] = {e4.x, e4.y, e4.z, e4.w};
      #pragma unroll
      for (int h = 0; h < 4; ++h) {
        float v = ee[h] + erh[h];
        v = v > 0.f ? v : NEG_SLOPE * v;
        den[h] += valid ? __expf(v - m[h]) : 0.f;
      }
    }
    #pragma unroll
    for (int h = 0; h < 4; ++h)
      #pragma unroll
      for (int o = 32; o > 0; o >>= 1) den[h] += __shfl_xor(den[h], o);
    float invd = 1.f / den[hh];
    for (int c = start; c < end; c += 64) {
      int i = c + lane;
      bool valid = i < end;
      int s = valid ? ssrc[i] : 0;
      float4 e4 = *(const float4*)&el[s * 4];
      float ee[4] = {e4.x, e4.y, e4.z, e4.w};
      float ex[4];
      #pragma unroll
      for (int h = 0; h < 4; ++h) {
        float v = ee[h] + erh[h];
        v = v > 0.f ? v : NEG_SLOPE * v;
        ex[h] = __expf(v - m[h]);
      }
      int cnt2 = min(64, end - c);
      for (int j = 0; j < cnt2; ++j) {
        int sj = __shfl(s, j);
        float a0 = __shfl(ex[0], j);
        float a1 = __shfl(ex[1], j);
        float a2 = __shfl(ex[2], j);
        float a3 = __shfl(ex[3], j);
        float ah = hh == 0 ? a0 : (hh == 1 ? a1 : (hh == 2 ? a2 : a3));
        ah *= invd;
        unsigned u = *(const unsigned*)&ftb[(size_t)sj * D_HID + f0];
        acc.x += ah * bfu_lo(u);
        acc.y += ah * bfu_hi(u);
      }
    }
  }
  *(float2*)&out[(size_t)n * D_HID + f0] = acc;
}

extern "C" void kernel_launch(void* const* d_in, const int* in_sizes, int n_in,
                              void* d_out, int out_size, void* d_ws, size_t ws_size,
                              hipStream_t stream) {
  const float* x      = (const float*)d_in[0];
  const float* fc_w   = (const float*)d_in[1];
  const float* attn_l = (const float*)d_in[2];
  const float* attn_r = (const float*)d_in[3];
  const int*   src    = (const int*)d_in[4];
  const int*   dst    = (const int*)d_in[5];
  float* out = (float*)d_out;

  char* wsp = (char*)d_ws;
  size_t off = 0;
  auto alloc = [&](size_t bytes) {
    void* p = wsp + off;
    off = (off + bytes + 255) & ~(size_t)255;
    return p;
  };
  unsigned short* ftb = (unsigned short*)alloc((size_t)N_NODES * D_HID * 2);
  float* el     = (float*)alloc((size_t)N_NODES * 4 * 4);
  float* er     = (float*)alloc((size_t)N_NODES * 4 * 4);
  int*   offs   = (int*)alloc((size_t)(N_NODES + 1) * 4);
  int*   ssrc   = (int*)alloc((size_t)N_EDGES * 4);
  int*   gfill  = (int*)alloc((size_t)NB * 4);
  int*   bbase  = (int*)alloc((size_t)NB * 4);
  unsigned* pairs = (unsigned*)alloc((size_t)NB * CAP * 4);

  hipMemsetAsync(gfill, 0, (size_t)NB * 4, stream);
  k_gemm<<<(N_NODES + 127) / 128, 256, 0, stream>>>(x, fc_w, ftb);
  k_eler<<<(N_NODES * N_HEADS + 255) / 256, 256, 0, stream>>>(ftb, attn_l, attn_r, el, er);
  k_bucket<<<N_TILES, 256, 0, stream>>>(src, dst, gfill, pairs);
  k_scanbuckets<<<1, 512, 0, stream>>>(gfill, bbase, offs);
  k_localsort<<<NB, 256, 0, stream>>>(pairs, gfill, bbase, offs, ssrc);
  k_agg<<<(N_NODES + 3) / 4, 256, 0, stream>>>(offs, ssrc, ftb, el, er, out);
}